// Round 2
// baseline (2420.602 us; speedup 1.0000x reference)
//
#include <hip/hip_runtime.h>

#define CH  128   // C: node feature channels
#define HID 128   // H: hidden channels
#define EAD 8     // edge_attr dim

// ---------------- helpers ----------------
__device__ __forceinline__ void load8(const float* __restrict__ p, float* r) {
    float4 v0 = *(const float4*)p;
    float4 v1 = *(const float4*)(p + 4);
    r[0]=v0.x; r[1]=v0.y; r[2]=v0.z; r[3]=v0.w;
    r[4]=v1.x; r[5]=v1.y; r[6]=v1.z; r[7]=v1.w;
}
__device__ __forceinline__ void store8(float* p, const float* v) {
    *(float4*)p       = make_float4(v[0], v[1], v[2], v[3]);
    *(float4*)(p + 4) = make_float4(v[4], v[5], v[6], v[7]);
}
__device__ __forceinline__ void zero48(float a[4][8]) {
#pragma unroll
    for (int i = 0; i < 4; i++)
#pragma unroll
        for (int j = 0; j < 8; j++) a[i][j] = 0.f;
}

// 64-row x 128-col register-tiled GEMM accumulate:
// acc[i][j] += sum_k sA[(te+16i)*strideA + k] * B[k*ldb + jb + j]
// strideA 132/260: 16 distinct per-wave ds_read_b128 addrs land 2-per-bank = free (m136).
template <int K>
__device__ __forceinline__ void gemm_tile(const float* sA, int strideA,
                                          const float* __restrict__ B, int ldb,
                                          int te, int jb, float acc[4][8]) {
#pragma unroll 2
    for (int k = 0; k < K; k += 4) {
        float av[4][4];
#pragma unroll
        for (int i = 0; i < 4; i++) {
            float4 t = *(const float4*)(sA + (te + 16 * i) * strideA + k);
            av[i][0] = t.x; av[i][1] = t.y; av[i][2] = t.z; av[i][3] = t.w;
        }
#pragma unroll
        for (int kk = 0; kk < 4; kk++) {
            float b8[8];
            load8(B + (size_t)(k + kk) * ldb + jb, b8);
#pragma unroll
            for (int i = 0; i < 4; i++)
#pragma unroll
                for (int j = 0; j < 8; j++)
                    acc[i][j] = fmaf(av[i][kk], b8[j], acc[i][j]);
        }
    }
}

// ---------------- kernel 1: per-node factored edge-MLP1 partials ----------------
// tbl[n][0:128]   = x[n] @ W_e1[0:128,:]   + b_e1   (the "x[row]" part, bias folded)
// tbl[n][128:256] = x[n] @ W_e1[128:256,:]          (the "x[col]" part)
__global__ __launch_bounds__(256, 2)
void precompute_kernel(const float* __restrict__ x, const float* __restrict__ w1,
                       const float* __restrict__ b1, float* __restrict__ tbl, int N) {
    __shared__ float sX[64 * 132];
    const int tid = threadIdx.x;
    const int n0  = blockIdx.x * 64;
    {
        const int n = tid >> 2, q = tid & 3;
        int gn = n0 + n; if (gn >= N) gn = N - 1;
        const float4* src = (const float4*)(x + (size_t)gn * CH + q * 32);
        float4* dst = (float4*)(sX + n * 132 + q * 32);
#pragma unroll
        for (int u = 0; u < 8; u++) dst[u] = src[u];
    }
    __syncthreads();
    const int te = tid & 15, jb = (tid >> 4) * 8;
    float acc[4][8];

    zero48(acc);
    gemm_tile<128>(sX, 132, w1, HID, te, jb, acc);          // rows 0..127 of w_e1
    float bb[8]; load8(b1 + jb, bb);
#pragma unroll
    for (int i = 0; i < 4; i++) {
        const int gn = n0 + te + 16 * i;
        if (gn < N) {
            float v[8];
#pragma unroll
            for (int j = 0; j < 8; j++) v[j] = acc[i][j] + bb[j];
            store8(tbl + (size_t)gn * 256 + jb, v);
        }
    }

    zero48(acc);
    gemm_tile<128>(sX, 132, w1 + CH * HID, HID, te, jb, acc); // rows 128..255 of w_e1
#pragma unroll
    for (int i = 0; i < 4; i++) {
        const int gn = n0 + te + 16 * i;
        if (gn < N) store8(tbl + (size_t)gn * 256 + 128 + jb, acc[i]);
    }
}

// ---------------- kernel 2: edge model + fused segment-sum (atomics) ----------------
// h1 = relu(tbl[row][0:128] + tbl[col][128:256] + radial*w_e1[256,:] + ea@w_e1[257:265,:])
// feat = relu(h1 @ w_e2 + b_e2);  agg[row] += feat
__global__ __launch_bounds__(256, 2)
void edge_kernel(const float* __restrict__ tbl, const float* __restrict__ coord,
                 const int* __restrict__ ei, const float* __restrict__ ea,
                 const float* __restrict__ w1, const float* __restrict__ w2,
                 const float* __restrict__ b2, float* agg, int E) {
    __shared__ float sH[64 * 132];
    __shared__ float sW[9 * 128];   // w_e1 rows 256..264 (radial + edge_attr), block-invariant
    const int tid = threadIdx.x;
    const int e0  = blockIdx.x * 64;

    // stage the 9 radial/ea weight rows once (4.6 KB; was 256 KB/block of L1 re-reads)
    for (int i = tid; i < 9 * 128; i += 256) sW[i] = w1[256 * HID + i];
    __syncthreads();

    // ---- stage h1 tile: 4 threads per edge, 32 channels each ----
    {
        const int e = tid >> 2, q = tid & 3;
        const int ge  = e0 + e;
        const int gec = (ge < E) ? ge : 0;
        const int r = ei[gec];
        const int c = ei[E + gec];
        const float dx = coord[3 * r + 0] - coord[3 * c + 0];
        const float dy = coord[3 * r + 1] - coord[3 * c + 1];
        const float dz = coord[3 * r + 2] - coord[3 * c + 2];
        const float radial = fmaf(dx, dx, fmaf(dy, dy, dz * dz));
        float eav[8];
        load8(ea + (size_t)gec * EAD, eav);
        const float* tr = tbl + (size_t)r * 256 + q * 32;        // x[row] partial (+b_e1)
        const float* tc = tbl + (size_t)c * 256 + 128 + q * 32;  // x[col] partial
        float* dst = sH + e * 132 + q * 32;
#pragma unroll
        for (int u = 0; u < 4; u++) {
            float hr[8], hc[8], wr[8], v[8];
            load8(tr + u * 8, hr);
            load8(tc + u * 8, hc);
            load8(sW + q * 32 + u * 8, wr);                      // radial row (broadcast LDS)
#pragma unroll
            for (int j = 0; j < 8; j++) v[j] = hr[j] + hc[j] + radial * wr[j];
#pragma unroll
            for (int m = 0; m < 8; m++) {
                float we[8];
                load8(sW + (1 + m) * 128 + q * 32 + u * 8, we);  // ea rows (broadcast LDS)
#pragma unroll
                for (int j = 0; j < 8; j++) v[j] = fmaf(eav[m], we[j], v[j]);
            }
#pragma unroll
            for (int j = 0; j < 8; j++) v[j] = fmaxf(v[j], 0.f);
            store8(dst + u * 8, v);
        }
    }
    __syncthreads();

    // ---- MLP2 over the h1 tile ----
    const int te = tid & 15, jb = (tid >> 4) * 8;
    float acc[4][8];
    zero48(acc);
    gemm_tile<128>(sH, 132, w2, HID, te, jb, acc);
    float bb[8]; load8(b2 + jb, bb);
#pragma unroll
    for (int i = 0; i < 4; i++) {
        const int ge = e0 + te + 16 * i;
        if (ge < E) {
            const int r = ei[ge];
            float* dst = agg + (size_t)r * HID + jb;
#pragma unroll
            for (int j = 0; j < 8; j++)
                atomicAdd(dst + j, fmaxf(acc[i][j] + bb[j], 0.f));
        }
    }
}

// ---------------- kernel 3: node model ----------------
// out = relu(concat(x, agg) @ w_n1 + b_n1) @ w_n2 + b_n2
// agg aliases out: each block stages its rows into LDS (reads complete before the
// barrier), then writes only its own rows at the end -> no cross-block hazard.
__global__ __launch_bounds__(256, 2)
void node_kernel(const float* __restrict__ x, const float* agg,
                 const float* __restrict__ w1, const float* __restrict__ b1,
                 const float* __restrict__ w2, const float* __restrict__ b2,
                 float* out, int N) {
    __shared__ float sA[64 * 260];
    const int tid = threadIdx.x;
    const int n0  = blockIdx.x * 64;
    {
        const int n = tid >> 2, q = tid & 3;
        int gn = n0 + n; if (gn >= N) gn = N - 1;
        const float4* sx = (const float4*)(x   + (size_t)gn * CH  + q * 32);
        const float4* sg = (const float4*)(agg + (size_t)gn * HID + q * 32);
        float4* dx4 = (float4*)(sA + n * 260 + q * 32);
        float4* dg4 = (float4*)(sA + n * 260 + CH + q * 32);
#pragma unroll
        for (int u = 0; u < 8; u++) { dx4[u] = sx[u]; dg4[u] = sg[u]; }
    }
    __syncthreads();
    const int te = tid & 15, jb = (tid >> 4) * 8;
    float acc[4][8];
    zero48(acc);
    gemm_tile<256>(sA, 260, w1, HID, te, jb, acc);
    float bb[8]; load8(b1 + jb, bb);
    float h[4][8];
#pragma unroll
    for (int i = 0; i < 4; i++)
#pragma unroll
        for (int j = 0; j < 8; j++) h[i][j] = fmaxf(acc[i][j] + bb[j], 0.f);
    __syncthreads();   // all MLP1 reads of sA complete
#pragma unroll
    for (int i = 0; i < 4; i++) store8(sA + (te + 16 * i) * 260 + jb, h[i]);
    __syncthreads();
    zero48(acc);
    gemm_tile<128>(sA, 260, w2, CH, te, jb, acc);
    float b2v[8]; load8(b2 + jb, b2v);
#pragma unroll
    for (int i = 0; i < 4; i++) {
        const int gn = n0 + te + 16 * i;
        if (gn < N) {
            float v[8];
#pragma unroll
            for (int j = 0; j < 8; j++) v[j] = acc[i][j] + b2v[j];
            store8(out + (size_t)gn * CH + jb, v);
        }
    }
}

// ---------------- launch ----------------
extern "C" void kernel_launch(void* const* d_in, const int* in_sizes, int n_in,
                              void* d_out, int out_size, void* d_ws, size_t ws_size,
                              hipStream_t stream) {
    const float* x     = (const float*)d_in[0];
    const float* coord = (const float*)d_in[1];
    const int*   ei    = (const int*)d_in[2];   // [2,E]: row = ei[0:E], col = ei[E:2E]
    const float* ea    = (const float*)d_in[3];
    const float* w_e1  = (const float*)d_in[4];
    const float* b_e1  = (const float*)d_in[5];
    const float* w_e2  = (const float*)d_in[6];
    const float* b_e2  = (const float*)d_in[7];
    const float* w_n1  = (const float*)d_in[8];
    const float* b_n1  = (const float*)d_in[9];
    const float* w_n2  = (const float*)d_in[10];
    const float* b_n2  = (const float*)d_in[11];

    const int N = in_sizes[0] / CH;
    const int E = in_sizes[2] / 2;

    float* out = (float*)d_out;
    float* agg = out;                 // agg lives in d_out (25.6 MB), aliased
    float* tbl = (float*)d_ws;        // [N][256] fp32 = 51.2 MB in workspace

    hipMemsetAsync(agg, 0, (size_t)N * HID * sizeof(float), stream);
    precompute_kernel<<<dim3((N + 63) / 64), dim3(256), 0, stream>>>(x, w_e1, b_e1, tbl, N);
    edge_kernel<<<dim3((E + 63) / 64), dim3(256), 0, stream>>>(tbl, coord, ei, ea,
                                                               w_e1, w_e2, b_e2, agg, E);
    node_kernel<<<dim3((N + 63) / 64), dim3(256), 0, stream>>>(x, agg, w_n1, b_n1,
                                                               w_n2, b_n2, out, N);
}

// Round 6
// 891.260 us; speedup vs baseline: 2.7159x; 2.7159x over previous
//
#include <hip/hip_runtime.h>

#define CH  128   // C: node feature channels
#define HID 128   // H: hidden channels
#define EAD 8     // edge_attr dim

// ---------------- helpers ----------------
__device__ __forceinline__ void load8(const float* __restrict__ p, float* r) {
    float4 v0 = *(const float4*)p;
    float4 v1 = *(const float4*)(p + 4);
    r[0]=v0.x; r[1]=v0.y; r[2]=v0.z; r[3]=v0.w;
    r[4]=v1.x; r[5]=v1.y; r[6]=v1.z; r[7]=v1.w;
}
__device__ __forceinline__ void store8(float* p, const float* v) {
    *(float4*)p       = make_float4(v[0], v[1], v[2], v[3]);
    *(float4*)(p + 4) = make_float4(v[4], v[5], v[6], v[7]);
}
__device__ __forceinline__ void zero48(float a[4][8]) {
#pragma unroll
    for (int i = 0; i < 4; i++)
#pragma unroll
        for (int j = 0; j < 8; j++) a[i][j] = 0.f;
}

// 64-row x 128-col register-tiled GEMM accumulate (strideA 132/260: per-wave
// ds_read_b128 addrs land 2-per-bank = free per m136).
template <int K>
__device__ __forceinline__ void gemm_tile(const float* sA, int strideA,
                                          const float* __restrict__ B, int ldb,
                                          int te, int jb, float acc[4][8]) {
#pragma unroll 2
    for (int k = 0; k < K; k += 4) {
        float av[4][4];
#pragma unroll
        for (int i = 0; i < 4; i++) {
            float4 t = *(const float4*)(sA + (te + 16 * i) * strideA + k);
            av[i][0] = t.x; av[i][1] = t.y; av[i][2] = t.z; av[i][3] = t.w;
        }
#pragma unroll
        for (int kk = 0; kk < 4; kk++) {
            float b8[8];
            load8(B + (size_t)(k + kk) * ldb + jb, b8);
#pragma unroll
            for (int i = 0; i < 4; i++)
#pragma unroll
                for (int j = 0; j < 8; j++)
                    acc[i][j] = fmaf(av[i][kk], b8[j], acc[i][j]);
        }
    }
}

// ---------------- kernel 1: per-node factored edge-MLP1 partials ----------------
// tbl[n][0:128]   = x[n] @ W_e1[0:128,:] + b_e1   ("x[row]" part, bias folded)
// tbl[n][128:256] = x[n] @ W_e1[128:256,:]        ("x[col]" part)
__global__ __launch_bounds__(256, 2)
void precompute_kernel(const float* __restrict__ x, const float* __restrict__ w1,
                       const float* __restrict__ b1, float* __restrict__ tbl, int N) {
    __shared__ float sX[64 * 132];
    const int tid = threadIdx.x;
    const int n0  = blockIdx.x * 64;
    {
        const int n = tid >> 2, q = tid & 3;
        int gn = n0 + n; if (gn >= N) gn = N - 1;
        const float4* src = (const float4*)(x + (size_t)gn * CH + q * 32);
        float4* dst = (float4*)(sX + n * 132 + q * 32);
#pragma unroll
        for (int u = 0; u < 8; u++) dst[u] = src[u];
    }
    __syncthreads();
    const int te = tid & 15, jb = (tid >> 4) * 8;
    float acc[4][8];

    zero48(acc);
    gemm_tile<128>(sX, 132, w1, HID, te, jb, acc);          // rows 0..127 of w_e1
    float bb[8]; load8(b1 + jb, bb);
#pragma unroll
    for (int i = 0; i < 4; i++) {
        const int gn = n0 + te + 16 * i;
        if (gn < N) {
            float v[8];
#pragma unroll
            for (int j = 0; j < 8; j++) v[j] = acc[i][j] + bb[j];
            store8(tbl + (size_t)gn * 256 + jb, v);
        }
    }

    zero48(acc);
    gemm_tile<128>(sX, 132, w1 + CH * HID, HID, te, jb, acc); // rows 128..255 of w_e1
#pragma unroll
    for (int i = 0; i < 4; i++) {
        const int gn = n0 + te + 16 * i;
        if (gn < N) store8(tbl + (size_t)gn * 256 + 128 + jb, acc[i]);
    }
}

// ---------------- CSR build: histogram -> scan -> scatter ----------------
__global__ void hist_kernel(const int* __restrict__ ei, int* __restrict__ deg, int E) {
    const int e = blockIdx.x * blockDim.x + threadIdx.x;
    if (e < E) atomicAdd(&deg[ei[e]], 1);
}

// single block, 1024 threads: exclusive scan of deg[N] -> row_ptr[N+1] and cursor[N]
__global__ void scan_kernel(const int* __restrict__ deg, int* __restrict__ row_ptr,
                            int* __restrict__ cursor, int N) {
    __shared__ int part[1024];
    const int tid = threadIdx.x;
    const int chunk = (N + 1023) / 1024;
    const int lo = tid * chunk;
    const int hi = (lo + chunk < N) ? lo + chunk : N;
    int s = 0;
    for (int i = lo; i < hi; i++) s += deg[i];
    part[tid] = s;
    __syncthreads();
    for (int off = 1; off < 1024; off <<= 1) {   // Hillis-Steele inclusive scan
        int v = (tid >= off) ? part[tid - off] : 0;
        __syncthreads();
        part[tid] += v;
        __syncthreads();
    }
    int run = (tid == 0) ? 0 : part[tid - 1];    // exclusive base
    for (int i = lo; i < hi; i++) {
        row_ptr[i] = run; cursor[i] = run;
        run += deg[i];
    }
    if (tid == 1023) row_ptr[N] = run;           // total = E
}

__global__ void scatter_kernel(const int* __restrict__ ei, int* cursor,
                               int* __restrict__ perm, int E) {
    const int e = blockIdx.x * blockDim.x + threadIdx.x;
    if (e < E) {
        const int p = atomicAdd(&cursor[ei[e]], 1);
        perm[p] = e;
    }
}

// ---------------- kernel 2: edge model over row-sorted edges + segmented reduce ----
// h1 = relu(tbl[row][0:128] + tbl[col][128:256] + radial*w_e1[256,:] + ea@w_e1[257:265,:])
// feat = relu(h1 @ w_e2 + b_e2); agg[row] = segment-sum(feat)  (plain stores for
// tile-interior rows, atomics only for tile-spanning boundary rows)
__global__ __launch_bounds__(256, 2)
void edge_kernel_sorted(const float* __restrict__ tbl, const float* __restrict__ coord,
                        const int* __restrict__ ei, const float* __restrict__ ea,
                        const float* __restrict__ w1, const float* __restrict__ w2,
                        const float* __restrict__ b2, const int* __restrict__ perm,
                        const int* __restrict__ row_ptr, float* agg, int E) {
    __shared__ float sH[64 * 132];
    __shared__ float sW[9 * 128];   // w_e1 rows 256..264 (radial + edge_attr)
    __shared__ int   sRow[64];      // sorted row id per tile slot
    const int tid = threadIdx.x;
    const int e0  = blockIdx.x * 64;   // E % 64 == 0: no tail

    for (int i = tid; i < 9 * 128; i += 256) sW[i] = w1[256 * HID + i];
    __syncthreads();

    // ---- stage h1 tile: 4 threads per edge slot, 32 channels each ----
    {
        const int s = tid >> 2, q = tid & 3;
        const int pe = perm[e0 + s];           // original edge id
        const int r = ei[pe];
        const int c = ei[E + pe];
        if (q == 0) sRow[s] = r;
        const float dx = coord[3 * r + 0] - coord[3 * c + 0];
        const float dy = coord[3 * r + 1] - coord[3 * c + 1];
        const float dz = coord[3 * r + 2] - coord[3 * c + 2];
        const float radial = fmaf(dx, dx, fmaf(dy, dy, dz * dz));
        float eav[8];
        load8(ea + (size_t)pe * EAD, eav);
        const float* tr = tbl + (size_t)r * 256 + q * 32;        // row partial (+b_e1)
        const float* tc = tbl + (size_t)c * 256 + 128 + q * 32;  // col partial
        float* dst = sH + s * 132 + q * 32;
#pragma unroll
        for (int u = 0; u < 4; u++) {
            float hr[8], hc[8], wr[8], v[8];
            load8(tr + u * 8, hr);
            load8(tc + u * 8, hc);
            load8(sW + q * 32 + u * 8, wr);                      // radial row (broadcast)
#pragma unroll
            for (int j = 0; j < 8; j++) v[j] = hr[j] + hc[j] + radial * wr[j];
#pragma unroll
            for (int m = 0; m < 8; m++) {
                float we[8];
                load8(sW + (1 + m) * 128 + q * 32 + u * 8, we);  // ea rows (broadcast)
#pragma unroll
                for (int j = 0; j < 8; j++) v[j] = fmaf(eav[m], we[j], v[j]);
            }
#pragma unroll
            for (int j = 0; j < 8; j++) v[j] = fmaxf(v[j], 0.f);
            store8(dst + u * 8, v);
        }
    }
    __syncthreads();

    // ---- MLP2 over the h1 tile ----
    const int te = tid & 15, jb = (tid >> 4) * 8;
    float acc[4][8];
    zero48(acc);
    gemm_tile<128>(sH, 132, w2, HID, te, jb, acc);
    float bb[8]; load8(b2 + jb, bb);
    __syncthreads();               // all gemm reads of sH complete before overwrite

    // ---- write relu(feat) tile back to LDS ----
#pragma unroll
    for (int i = 0; i < 4; i++) {
        float v[8];
#pragma unroll
        for (int j = 0; j < 8; j++) v[j] = fmaxf(acc[i][j] + bb[j], 0.f);
        store8(sH + (te + 16 * i) * 132 + jb, v);
    }
    __syncthreads();

    // ---- segmented reduction: one head thread-quad per distinct row ----
    {
        const int s = tid >> 2, q = tid & 3;
        const int r = sRow[s];
        const bool head = (s == 0) || (sRow[s - 1] != r);
        if (head) {
            float sum[32];
            const float* src = sH + s * 132 + q * 32;
#pragma unroll
            for (int j = 0; j < 32; j += 4) {
                float4 t = *(const float4*)(src + j);
                sum[j] = t.x; sum[j+1] = t.y; sum[j+2] = t.z; sum[j+3] = t.w;
            }
            int L = 1;
            while (s + L < 64 && sRow[s + L] == r) {
                const float* p = sH + (s + L) * 132 + q * 32;
#pragma unroll
                for (int j = 0; j < 32; j += 4) {
                    float4 t = *(const float4*)(p + j);
                    sum[j] += t.x; sum[j+1] += t.y; sum[j+2] += t.z; sum[j+3] += t.w;
                }
                L++;
            }
            float* dst = agg + (size_t)r * HID + q * 32;
            const bool interior = (row_ptr[r] >= e0) && (row_ptr[r + 1] <= e0 + 64);
            if (interior) {     // this tile holds ALL edges of row r -> plain store
#pragma unroll
                for (int j = 0; j < 32; j += 4)
                    *(float4*)(dst + j) = make_float4(sum[j], sum[j+1], sum[j+2], sum[j+3]);
            } else {            // row spans tiles -> atomic (rare: ~2 rows/tile)
#pragma unroll
                for (int j = 0; j < 32; j++) atomicAdd(dst + j, sum[j]);
            }
        }
    }
}

// ---------------- kernel 3: node model ----------------
// out = relu(concat(x, agg) @ w_n1 + b_n1) @ w_n2 + b_n2
// agg aliases out: each block stages its rows into LDS before overwriting them.
__global__ __launch_bounds__(256, 2)
void node_kernel(const float* __restrict__ x, const float* agg,
                 const float* __restrict__ w1, const float* __restrict__ b1,
                 const float* __restrict__ w2, const float* __restrict__ b2,
                 float* out, int N) {
    __shared__ float sA[64 * 260];
    const int tid = threadIdx.x;
    const int n0  = blockIdx.x * 64;
    {
        const int n = tid >> 2, q = tid & 3;
        int gn = n0 + n; if (gn >= N) gn = N - 1;
        const float4* sx = (const float4*)(x   + (size_t)gn * CH  + q * 32);
        const float4* sg = (const float4*)(agg + (size_t)gn * HID + q * 32);
        float4* dx4 = (float4*)(sA + n * 260 + q * 32);
        float4* dg4 = (float4*)(sA + n * 260 + CH + q * 32);
#pragma unroll
        for (int u = 0; u < 8; u++) { dx4[u] = sx[u]; dg4[u] = sg[u]; }
    }
    __syncthreads();
    const int te = tid & 15, jb = (tid >> 4) * 8;
    float acc[4][8];
    zero48(acc);
    gemm_tile<256>(sA, 260, w1, HID, te, jb, acc);
    float bb[8]; load8(b1 + jb, bb);
    float h[4][8];
#pragma unroll
    for (int i = 0; i < 4; i++)
#pragma unroll
        for (int j = 0; j < 8; j++) h[i][j] = fmaxf(acc[i][j] + bb[j], 0.f);
    __syncthreads();
#pragma unroll
    for (int i = 0; i < 4; i++) store8(sA + (te + 16 * i) * 260 + jb, h[i]);
    __syncthreads();
    zero48(acc);
    gemm_tile<128>(sA, 260, w2, CH, te, jb, acc);
    float b2v[8]; load8(b2 + jb, b2v);
#pragma unroll
    for (int i = 0; i < 4; i++) {
        const int gn = n0 + te + 16 * i;
        if (gn < N) {
            float v[8];
#pragma unroll
            for (int j = 0; j < 8; j++) v[j] = acc[i][j] + b2v[j];
            store8(out + (size_t)gn * CH + jb, v);
        }
    }
}

// ---------------- launch ----------------
extern "C" void kernel_launch(void* const* d_in, const int* in_sizes, int n_in,
                              void* d_out, int out_size, void* d_ws, size_t ws_size,
                              hipStream_t stream) {
    const float* x     = (const float*)d_in[0];
    const float* coord = (const float*)d_in[1];
    const int*   ei    = (const int*)d_in[2];   // [2,E]: row = ei[0:E], col = ei[E:2E]
    const float* ea    = (const float*)d_in[3];
    const float* w_e1  = (const float*)d_in[4];
    const float* b_e1  = (const float*)d_in[5];
    const float* w_e2  = (const float*)d_in[6];
    const float* b_e2  = (const float*)d_in[7];
    const float* w_n1  = (const float*)d_in[8];
    const float* b_n1  = (const float*)d_in[9];
    const float* w_n2  = (const float*)d_in[10];
    const float* b_n2  = (const float*)d_in[11];

    const int N = in_sizes[0] / CH;
    const int E = in_sizes[2] / 2;

    float* out = (float*)d_out;
    float* agg = out;                 // agg lives in d_out, aliased

    // workspace carve (all 16B-aligned): tbl | perm | deg | row_ptr | cursor
    char* w = (char*)d_ws;
    float* tbl   = (float*)w;  w += (size_t)N * 256 * sizeof(float);   // 51.2 MB
    int* perm    = (int*)w;    w += (size_t)E * sizeof(int);           // 2.4 MB
    int* deg     = (int*)w;    w += (size_t)N * sizeof(int);
    int* row_ptr = (int*)w;    w += (size_t)(N + 1) * sizeof(int);
    int* cursor  = (int*)w;

    hipMemsetAsync(agg, 0, (size_t)N * HID * sizeof(float), stream);
    hipMemsetAsync(deg, 0, (size_t)N * sizeof(int), stream);

    precompute_kernel<<<dim3((N + 63) / 64), dim3(256), 0, stream>>>(x, w_e1, b_e1, tbl, N);
    hist_kernel<<<dim3((E + 255) / 256), dim3(256), 0, stream>>>(ei, deg, E);
    scan_kernel<<<dim3(1), dim3(1024), 0, stream>>>(deg, row_ptr, cursor, N);
    scatter_kernel<<<dim3((E + 255) / 256), dim3(256), 0, stream>>>(ei, cursor, perm, E);
    edge_kernel_sorted<<<dim3(E / 64), dim3(256), 0, stream>>>(tbl, coord, ei, ea,
                                                               w_e1, w_e2, b_e2,
                                                               perm, row_ptr, agg, E);
    node_kernel<<<dim3((N + 63) / 64), dim3(256), 0, stream>>>(x, agg, w_n1, b_n1,
                                                               w_n2, b_n2, out, N);
}

// Round 7
// 793.445 us; speedup vs baseline: 3.0507x; 1.1233x over previous
//
#include <hip/hip_runtime.h>

#define CH  128   // C: node feature channels
#define HID 128   // H: hidden channels
#define EAD 8     // edge_attr dim

// ---------------- helpers ----------------
__device__ __forceinline__ void load8(const float* __restrict__ p, float* r) {
    float4 v0 = *(const float4*)p;
    float4 v1 = *(const float4*)(p + 4);
    r[0]=v0.x; r[1]=v0.y; r[2]=v0.z; r[3]=v0.w;
    r[4]=v1.x; r[5]=v1.y; r[6]=v1.z; r[7]=v1.w;
}
__device__ __forceinline__ void store8(float* p, const float* v) {
    *(float4*)p       = make_float4(v[0], v[1], v[2], v[3]);
    *(float4*)(p + 4) = make_float4(v[4], v[5], v[6], v[7]);
}
__device__ __forceinline__ void zero48(float a[4][8]) {
#pragma unroll
    for (int i = 0; i < 4; i++)
#pragma unroll
        for (int j = 0; j < 8; j++) a[i][j] = 0.f;
}

// 64-row x 128-col register-tiled GEMM accumulate, 4x8 per thread (256 threads).
template <int K>
__device__ __forceinline__ void gemm_tile(const float* sA, int strideA,
                                          const float* __restrict__ B, int ldb,
                                          int te, int jb, float acc[4][8]) {
#pragma unroll 2
    for (int k = 0; k < K; k += 4) {
        float av[4][4];
#pragma unroll
        for (int i = 0; i < 4; i++) {
            float4 t = *(const float4*)(sA + (te + 16 * i) * strideA + k);
            av[i][0] = t.x; av[i][1] = t.y; av[i][2] = t.z; av[i][3] = t.w;
        }
#pragma unroll
        for (int kk = 0; kk < 4; kk++) {
            float b8[8];
            load8(B + (size_t)(k + kk) * ldb + jb, b8);
#pragma unroll
            for (int i = 0; i < 4; i++)
#pragma unroll
                for (int j = 0; j < 8; j++)
                    acc[i][j] = fmaf(av[i][kk], b8[j], acc[i][j]);
        }
    }
}

// ---------------- kernel 1: per-node factored edge-MLP1 partials ----------------
// tbl[n][0:128]   = x[n] @ W_e1[0:128,:] + b_e1   ("x[row]" part, bias folded)
// tbl[n][128:256] = x[n] @ W_e1[128:256,:]        ("x[col]" part)
__global__ __launch_bounds__(256, 2)
void precompute_kernel(const float* __restrict__ x, const float* __restrict__ w1,
                       const float* __restrict__ b1, float* __restrict__ tbl, int N) {
    __shared__ float sX[64 * 132];
    const int tid = threadIdx.x;
    const int n0  = blockIdx.x * 64;
    {
        const int n = tid >> 2, q = tid & 3;
        int gn = n0 + n; if (gn >= N) gn = N - 1;
        const float4* src = (const float4*)(x + (size_t)gn * CH + q * 32);
        float4* dst = (float4*)(sX + n * 132 + q * 32);
#pragma unroll
        for (int u = 0; u < 8; u++) dst[u] = src[u];
    }
    __syncthreads();
    const int te = tid & 15, jb = (tid >> 4) * 8;
    float acc[4][8];

    zero48(acc);
    gemm_tile<128>(sX, 132, w1, HID, te, jb, acc);          // rows 0..127 of w_e1
    float bb[8]; load8(b1 + jb, bb);
#pragma unroll
    for (int i = 0; i < 4; i++) {
        const int gn = n0 + te + 16 * i;
        if (gn < N) {
            float v[8];
#pragma unroll
            for (int j = 0; j < 8; j++) v[j] = acc[i][j] + bb[j];
            store8(tbl + (size_t)gn * 256 + jb, v);
        }
    }

    zero48(acc);
    gemm_tile<128>(sX, 132, w1 + CH * HID, HID, te, jb, acc); // rows 128..255 of w_e1
#pragma unroll
    for (int i = 0; i < 4; i++) {
        const int gn = n0 + te + 16 * i;
        if (gn < N) store8(tbl + (size_t)gn * 256 + 128 + jb, acc[i]);
    }
}

// ---------------- CSR build: histogram -> scan -> scatter ----------------
__global__ void hist_kernel(const int* __restrict__ ei, int* __restrict__ deg, int E) {
    const int e = blockIdx.x * blockDim.x + threadIdx.x;
    if (e < E) atomicAdd(&deg[ei[e]], 1);
}

// single block, 1024 threads: exclusive scan of deg[N] -> row_ptr[N+1] and cursor[N]
__global__ void scan_kernel(const int* __restrict__ deg, int* __restrict__ row_ptr,
                            int* __restrict__ cursor, int N) {
    __shared__ int part[1024];
    const int tid = threadIdx.x;
    const int chunk = (N + 1023) / 1024;
    const int lo = tid * chunk;
    const int hi = (lo + chunk < N) ? lo + chunk : N;
    int s = 0;
    for (int i = lo; i < hi; i++) s += deg[i];
    part[tid] = s;
    __syncthreads();
    for (int off = 1; off < 1024; off <<= 1) {   // Hillis-Steele inclusive scan
        int v = (tid >= off) ? part[tid - off] : 0;
        __syncthreads();
        part[tid] += v;
        __syncthreads();
    }
    int run = (tid == 0) ? 0 : part[tid - 1];    // exclusive base
    for (int i = lo; i < hi; i++) {
        row_ptr[i] = run; cursor[i] = run;
        run += deg[i];
    }
    if (tid == 1023) row_ptr[N] = run;           // total = E
}

__global__ void scatter_kernel(const int* __restrict__ ei, int* cursor,
                               int* __restrict__ perm, int E) {
    const int e = blockIdx.x * blockDim.x + threadIdx.x;
    if (e < E) {
        const int p = atomicAdd(&cursor[ei[e]], 1);
        perm[p] = e;
    }
}

// ---------------- kernel 2: edge model over row-sorted edges + segmented reduce ----
// 128 threads, 64-edge tile, 8x8 register tile per thread in the MLP2 GEMM
// (32 FMA per global B-load, 8 broadcast LDS reads per k-group). Bijective XCD
// swizzle groups consecutive sorted tiles on one XCD for L2 reuse of tbl/w2.
__global__ __launch_bounds__(128, 2)
void edge_kernel_sorted(const float* __restrict__ tbl, const float* __restrict__ coord,
                        const int* __restrict__ ei, const float* __restrict__ ea,
                        const float* __restrict__ w1, const float* __restrict__ w2,
                        const float* __restrict__ b2, const int* __restrict__ perm,
                        const int* __restrict__ row_ptr, float* agg, int E) {
    __shared__ float sH[64 * 132];
    __shared__ float sW[9 * 128];   // w_e1 rows 256..264 (radial + edge_attr)
    __shared__ int   sRow[64];      // sorted row id per tile slot
    const int tid = threadIdx.x;

    // bijective XCD swizzle (m204): nwg need not be divisible by 8
    const int nwg = gridDim.x;
    const int qq = nwg >> 3, rr = nwg & 7;
    const int xcd = blockIdx.x & 7, idx = blockIdx.x >> 3;
    const int wg  = (xcd < rr) ? (xcd * (qq + 1) + idx)
                               : (rr * (qq + 1) + (xcd - rr) * qq + idx);
    const int e0  = wg * 64;           // E % 64 == 0: no tail

    for (int i = tid; i < 9 * 128; i += 128) sW[i] = w1[256 * HID + i];
    __syncthreads();

    // ---- stage h1 tile: 2 threads per edge slot, 64 channels each ----
    {
        const int s = tid >> 1, q = tid & 1;
        const int pe = perm[e0 + s];           // original edge id
        const int r = ei[pe];
        const int c = ei[E + pe];
        if (q == 0) sRow[s] = r;
        const float dx = coord[3 * r + 0] - coord[3 * c + 0];
        const float dy = coord[3 * r + 1] - coord[3 * c + 1];
        const float dz = coord[3 * r + 2] - coord[3 * c + 2];
        const float radial = fmaf(dx, dx, fmaf(dy, dy, dz * dz));
        float eav[8];
        load8(ea + (size_t)pe * EAD, eav);
        const float* tr = tbl + (size_t)r * 256 + q * 64;        // row partial (+b_e1)
        const float* tc = tbl + (size_t)c * 256 + 128 + q * 64;  // col partial
        float* dst = sH + s * 132 + q * 64;
#pragma unroll
        for (int u = 0; u < 8; u++) {
            float hr[8], hc[8], wr[8], v[8];
            load8(tr + u * 8, hr);
            load8(tc + u * 8, hc);
            load8(sW + q * 64 + u * 8, wr);                      // radial row (broadcast)
#pragma unroll
            for (int j = 0; j < 8; j++) v[j] = hr[j] + hc[j] + radial * wr[j];
#pragma unroll
            for (int m = 0; m < 8; m++) {
                float we[8];
                load8(sW + (1 + m) * 128 + q * 64 + u * 8, we);  // ea rows (broadcast)
#pragma unroll
                for (int j = 0; j < 8; j++) v[j] = fmaf(eav[m], we[j], v[j]);
            }
#pragma unroll
            for (int j = 0; j < 8; j++) v[j] = fmaxf(v[j], 0.f);
            store8(dst + u * 8, v);
        }
    }
    __syncthreads();

    // ---- MLP2: 8x8 register tile, rows tr8+8i, cols jb..jb+7 ----
    const int tr8 = tid & 7, jb = (tid >> 3) * 8;
    float acc[8][8];
#pragma unroll
    for (int i = 0; i < 8; i++)
#pragma unroll
        for (int j = 0; j < 8; j++) acc[i][j] = 0.f;
#pragma unroll 2
    for (int k = 0; k < 128; k += 4) {
        float av[8][4];
#pragma unroll
        for (int i = 0; i < 8; i++) {
            float4 t = *(const float4*)(sH + (tr8 + 8 * i) * 132 + k);
            av[i][0] = t.x; av[i][1] = t.y; av[i][2] = t.z; av[i][3] = t.w;
        }
#pragma unroll
        for (int kk = 0; kk < 4; kk++) {
            float b8[8];
            load8(w2 + (size_t)(k + kk) * HID + jb, b8);
#pragma unroll
            for (int i = 0; i < 8; i++)
#pragma unroll
                for (int j = 0; j < 8; j++)
                    acc[i][j] = fmaf(av[i][kk], b8[j], acc[i][j]);
        }
    }
    float bb[8]; load8(b2 + jb, bb);
    __syncthreads();               // all gemm reads of sH complete before overwrite

    // ---- write relu(feat) tile back to LDS ----
#pragma unroll
    for (int i = 0; i < 8; i++) {
        float v[8];
#pragma unroll
        for (int j = 0; j < 8; j++) v[j] = fmaxf(acc[i][j] + bb[j], 0.f);
        store8(sH + (tr8 + 8 * i) * 132 + jb, v);
    }
    __syncthreads();

    // ---- segmented reduction: 2 passes of 32 slots, 4 threads (32ch) per slot ----
#pragma unroll
    for (int base = 0; base < 64; base += 32) {
        const int s = base + (tid >> 2), q4 = tid & 3;
        const int r = sRow[s];
        const bool head = (s == 0) || (sRow[s - 1] != r);
        if (head) {
            float sum[32];
            const float* src = sH + s * 132 + q4 * 32;
#pragma unroll
            for (int j = 0; j < 32; j += 4) {
                float4 t = *(const float4*)(src + j);
                sum[j] = t.x; sum[j+1] = t.y; sum[j+2] = t.z; sum[j+3] = t.w;
            }
            int L = 1;
            while (s + L < 64 && sRow[s + L] == r) {
                const float* p = sH + (s + L) * 132 + q4 * 32;
#pragma unroll
                for (int j = 0; j < 32; j += 4) {
                    float4 t = *(const float4*)(p + j);
                    sum[j] += t.x; sum[j+1] += t.y; sum[j+2] += t.z; sum[j+3] += t.w;
                }
                L++;
            }
            float* dst = agg + (size_t)r * HID + q4 * 32;
            const bool interior = (row_ptr[r] >= e0) && (row_ptr[r + 1] <= e0 + 64);
            if (interior) {     // this tile holds ALL edges of row r -> plain store
#pragma unroll
                for (int j = 0; j < 32; j += 4)
                    *(float4*)(dst + j) = make_float4(sum[j], sum[j+1], sum[j+2], sum[j+3]);
            } else {            // row spans tiles -> atomic (rare: ~2 rows/tile)
#pragma unroll
                for (int j = 0; j < 32; j++) atomicAdd(dst + j, sum[j]);
            }
        }
    }
}

// ---------------- kernel 3: node model ----------------
// out = relu(concat(x, agg) @ w_n1 + b_n1) @ w_n2 + b_n2
// agg aliases out: each block stages its rows into LDS before overwriting them.
__global__ __launch_bounds__(256, 2)
void node_kernel(const float* __restrict__ x, const float* agg,
                 const float* __restrict__ w1, const float* __restrict__ b1,
                 const float* __restrict__ w2, const float* __restrict__ b2,
                 float* out, int N) {
    __shared__ float sA[64 * 260];
    const int tid = threadIdx.x;
    const int n0  = blockIdx.x * 64;
    {
        const int n = tid >> 2, q = tid & 3;
        int gn = n0 + n; if (gn >= N) gn = N - 1;
        const float4* sx = (const float4*)(x   + (size_t)gn * CH  + q * 32);
        const float4* sg = (const float4*)(agg + (size_t)gn * HID + q * 32);
        float4* dx4 = (float4*)(sA + n * 260 + q * 32);
        float4* dg4 = (float4*)(sA + n * 260 + CH + q * 32);
#pragma unroll
        for (int u = 0; u < 8; u++) { dx4[u] = sx[u]; dg4[u] = sg[u]; }
    }
    __syncthreads();
    const int te = tid & 15, jb = (tid >> 4) * 8;
    float acc[4][8];
    zero48(acc);
    gemm_tile<256>(sA, 260, w1, HID, te, jb, acc);
    float bb[8]; load8(b1 + jb, bb);
    float h[4][8];
#pragma unroll
    for (int i = 0; i < 4; i++)
#pragma unroll
        for (int j = 0; j < 8; j++) h[i][j] = fmaxf(acc[i][j] + bb[j], 0.f);
    __syncthreads();
#pragma unroll
    for (int i = 0; i < 4; i++) store8(sA + (te + 16 * i) * 260 + jb, h[i]);
    __syncthreads();
    zero48(acc);
    gemm_tile<128>(sA, 260, w2, CH, te, jb, acc);
    float b2v[8]; load8(b2 + jb, b2v);
#pragma unroll
    for (int i = 0; i < 4; i++) {
        const int gn = n0 + te + 16 * i;
        if (gn < N) {
            float v[8];
#pragma unroll
            for (int j = 0; j < 8; j++) v[j] = acc[i][j] + b2v[j];
            store8(out + (size_t)gn * CH + jb, v);
        }
    }
}

// ---------------- launch ----------------
extern "C" void kernel_launch(void* const* d_in, const int* in_sizes, int n_in,
                              void* d_out, int out_size, void* d_ws, size_t ws_size,
                              hipStream_t stream) {
    const float* x     = (const float*)d_in[0];
    const float* coord = (const float*)d_in[1];
    const int*   ei    = (const int*)d_in[2];   // [2,E]: row = ei[0:E], col = ei[E:2E]
    const float* ea    = (const float*)d_in[3];
    const float* w_e1  = (const float*)d_in[4];
    const float* b_e1  = (const float*)d_in[5];
    const float* w_e2  = (const float*)d_in[6];
    const float* b_e2  = (const float*)d_in[7];
    const float* w_n1  = (const float*)d_in[8];
    const float* b_n1  = (const float*)d_in[9];
    const float* w_n2  = (const float*)d_in[10];
    const float* b_n2  = (const float*)d_in[11];

    const int N = in_sizes[0] / CH;
    const int E = in_sizes[2] / 2;

    float* out = (float*)d_out;
    float* agg = out;                 // agg lives in d_out, aliased

    // workspace carve (all 16B-aligned): tbl | perm | deg | row_ptr | cursor
    char* w = (char*)d_ws;
    float* tbl   = (float*)w;  w += (size_t)N * 256 * sizeof(float);   // 51.2 MB
    int* perm    = (int*)w;    w += (size_t)E * sizeof(int);           // 2.4 MB
    int* deg     = (int*)w;    w += (size_t)N * sizeof(int);
    int* row_ptr = (int*)w;    w += (size_t)(N + 1) * sizeof(int);
    int* cursor  = (int*)w;

    hipMemsetAsync(agg, 0, (size_t)N * HID * sizeof(float), stream);
    hipMemsetAsync(deg, 0, (size_t)N * sizeof(int), stream);

    precompute_kernel<<<dim3((N + 63) / 64), dim3(256), 0, stream>>>(x, w_e1, b_e1, tbl, N);
    hist_kernel<<<dim3((E + 255) / 256), dim3(256), 0, stream>>>(ei, deg, E);
    scan_kernel<<<dim3(1), dim3(1024), 0, stream>>>(deg, row_ptr, cursor, N);
    scatter_kernel<<<dim3((E + 255) / 256), dim3(256), 0, stream>>>(ei, cursor, perm, E);
    edge_kernel_sorted<<<dim3(E / 64), dim3(128), 0, stream>>>(tbl, coord, ei, ea,
                                                               w_e1, w_e2, b_e2,
                                                               perm, row_ptr, agg, E);
    node_kernel<<<dim3((N + 63) / 64), dim3(256), 0, stream>>>(x, agg, w_n1, b_n1,
                                                               w_n2, b_n2, out, N);
}

// Round 10
// 749.622 us; speedup vs baseline: 3.2291x; 1.0585x over previous
//
#include <hip/hip_runtime.h>

#define CH  128   // C: node feature channels
#define HID 128   // H: hidden channels
#define EAD 8     // edge_attr dim

// ---------------- helpers ----------------
__device__ __forceinline__ void load8(const float* __restrict__ p, float* r) {
    float4 v0 = *(const float4*)p;
    float4 v1 = *(const float4*)(p + 4);
    r[0]=v0.x; r[1]=v0.y; r[2]=v0.z; r[3]=v0.w;
    r[4]=v1.x; r[5]=v1.y; r[6]=v1.z; r[7]=v1.w;
}
__device__ __forceinline__ void store8(float* p, const float* v) {
    *(float4*)p       = make_float4(v[0], v[1], v[2], v[3]);
    *(float4*)(p + 4) = make_float4(v[4], v[5], v[6], v[7]);
}
__device__ __forceinline__ void zero88(float a[8][8]) {
#pragma unroll
    for (int i = 0; i < 8; i++)
#pragma unroll
        for (int j = 0; j < 8; j++) a[i][j] = 0.f;
}

// 64-row x 128-col GEMM accumulate, 8x8 register tile, 128 threads.
// A-reads: 8 distinct broadcast LDS addresses per wave (conflict-free, stride
// 132/260 ≡ 4 mod 32 banks); 32 FMA per global B-load. Proven +23% vs 4x8 (r7).
template <int K>
__device__ __forceinline__ void gemm_tile8(const float* sA, int strideA,
                                           const float* __restrict__ B, int ldb,
                                           int tr8, int jb, float acc[8][8]) {
#pragma unroll 2
    for (int k = 0; k < K; k += 4) {
        float av[8][4];
#pragma unroll
        for (int i = 0; i < 8; i++) {
            float4 t = *(const float4*)(sA + (tr8 + 8 * i) * strideA + k);
            av[i][0] = t.x; av[i][1] = t.y; av[i][2] = t.z; av[i][3] = t.w;
        }
#pragma unroll
        for (int kk = 0; kk < 4; kk++) {
            float b8[8];
            load8(B + (size_t)(k + kk) * ldb + jb, b8);
#pragma unroll
            for (int i = 0; i < 8; i++)
#pragma unroll
                for (int j = 0; j < 8; j++)
                    acc[i][j] = fmaf(av[i][kk], b8[j], acc[i][j]);
        }
    }
}

// ---------------- kernel 1: per-node factored edge-MLP1 partials ----------------
// tbl[n][0:128]   = x[n] @ W_e1[0:128,:] + b_e1   ("x[row]" part, bias folded)
// tbl[n][128:256] = x[n] @ W_e1[128:256,:]        ("x[col]" part)
__global__ __launch_bounds__(128, 2)
void precompute_kernel(const float* __restrict__ x, const float* __restrict__ w1,
                       const float* __restrict__ b1, float* __restrict__ tbl, int N) {
    __shared__ float sX[64 * 132];
    const int tid = threadIdx.x;
    const int n0  = blockIdx.x * 64;
    {
        const int n = tid >> 1, q = tid & 1;
        int gn = n0 + n; if (gn >= N) gn = N - 1;
        const float4* src = (const float4*)(x + (size_t)gn * CH + q * 64);
        float4* dst = (float4*)(sX + n * 132 + q * 64);
#pragma unroll
        for (int u = 0; u < 16; u++) dst[u] = src[u];
    }
    __syncthreads();
    const int tr8 = tid & 7, jb = (tid >> 3) * 8;
    float acc[8][8];

    zero88(acc);
    gemm_tile8<128>(sX, 132, w1, HID, tr8, jb, acc);          // rows 0..127 of w_e1
    float bb[8]; load8(b1 + jb, bb);
#pragma unroll
    for (int i = 0; i < 8; i++) {
        const int gn = n0 + tr8 + 8 * i;
        if (gn < N) {
            float v[8];
#pragma unroll
            for (int j = 0; j < 8; j++) v[j] = acc[i][j] + bb[j];
            store8(tbl + (size_t)gn * 256 + jb, v);
        }
    }

    zero88(acc);
    gemm_tile8<128>(sX, 132, w1 + CH * HID, HID, tr8, jb, acc); // rows 128..255
#pragma unroll
    for (int i = 0; i < 8; i++) {
        const int gn = n0 + tr8 + 8 * i;
        if (gn < N) store8(tbl + (size_t)gn * 256 + 128 + jb, acc[i]);
    }
}

// ---------------- CSR build: histogram -> scan -> scatter ----------------
__global__ void hist_kernel(const int* __restrict__ ei, int* __restrict__ deg, int E) {
    const int e = blockIdx.x * blockDim.x + threadIdx.x;
    if (e < E) atomicAdd(&deg[ei[e]], 1);
}

// single block, 1024 threads: exclusive scan of deg[N] -> row_ptr[N+1] and cursor[N]
__global__ void scan_kernel(const int* __restrict__ deg, int* __restrict__ row_ptr,
                            int* __restrict__ cursor, int N) {
    __shared__ int part[1024];
    const int tid = threadIdx.x;
    const int chunk = (N + 1023) / 1024;
    const int lo = tid * chunk;
    const int hi = (lo + chunk < N) ? lo + chunk : N;
    int s = 0;
    for (int i = lo; i < hi; i++) s += deg[i];
    part[tid] = s;
    __syncthreads();
    for (int off = 1; off < 1024; off <<= 1) {   // Hillis-Steele inclusive scan
        int v = (tid >= off) ? part[tid - off] : 0;
        __syncthreads();
        part[tid] += v;
        __syncthreads();
    }
    int run = (tid == 0) ? 0 : part[tid - 1];    // exclusive base
    for (int i = lo; i < hi; i++) {
        row_ptr[i] = run; cursor[i] = run;
        run += deg[i];
    }
    if (tid == 1023) row_ptr[N] = run;           // total = E
}

__global__ void scatter_kernel(const int* __restrict__ ei, int* cursor,
                               int* __restrict__ perm, int E) {
    const int e = blockIdx.x * blockDim.x + threadIdx.x;
    if (e < E) {
        const int p = atomicAdd(&cursor[ei[e]], 1);
        perm[p] = e;
    }
}

// ---------------- kernel 2: edge model over row-sorted edges + segmented reduce ----
// (FROZEN from round 7: 384 us, VALU 52%. Only change: MLP2 via shared gemm_tile8,
// bit-identical loop structure.)
__global__ __launch_bounds__(128, 2)
void edge_kernel_sorted(const float* __restrict__ tbl, const float* __restrict__ coord,
                        const int* __restrict__ ei, const float* __restrict__ ea,
                        const float* __restrict__ w1, const float* __restrict__ w2,
                        const float* __restrict__ b2, const int* __restrict__ perm,
                        const int* __restrict__ row_ptr, float* agg, int E) {
    __shared__ float sH[64 * 132];
    __shared__ float sW[9 * 128];   // w_e1 rows 256..264 (radial + edge_attr)
    __shared__ int   sRow[64];      // sorted row id per tile slot
    const int tid = threadIdx.x;

    // bijective XCD swizzle (m204): nwg need not be divisible by 8
    const int nwg = gridDim.x;
    const int qq = nwg >> 3, rr = nwg & 7;
    const int xcd = blockIdx.x & 7, idx = blockIdx.x >> 3;
    const int wg  = (xcd < rr) ? (xcd * (qq + 1) + idx)
                               : (rr * (qq + 1) + (xcd - rr) * qq + idx);
    const int e0  = wg * 64;           // E % 64 == 0: no tail

    for (int i = tid; i < 9 * 128; i += 128) sW[i] = w1[256 * HID + i];
    __syncthreads();

    // ---- stage h1 tile: 2 threads per edge slot, 64 channels each ----
    {
        const int s = tid >> 1, q = tid & 1;
        const int pe = perm[e0 + s];           // original edge id
        const int r = ei[pe];
        const int c = ei[E + pe];
        if (q == 0) sRow[s] = r;
        const float dx = coord[3 * r + 0] - coord[3 * c + 0];
        const float dy = coord[3 * r + 1] - coord[3 * c + 1];
        const float dz = coord[3 * r + 2] - coord[3 * c + 2];
        const float radial = fmaf(dx, dx, fmaf(dy, dy, dz * dz));
        float eav[8];
        load8(ea + (size_t)pe * EAD, eav);
        const float* tr = tbl + (size_t)r * 256 + q * 64;        // row partial (+b_e1)
        const float* tc = tbl + (size_t)c * 256 + 128 + q * 64;  // col partial
        float* dst = sH + s * 132 + q * 64;
#pragma unroll
        for (int u = 0; u < 8; u++) {
            float hr[8], hc[8], wr[8], v[8];
            load8(tr + u * 8, hr);
            load8(tc + u * 8, hc);
            load8(sW + q * 64 + u * 8, wr);                      // radial row (broadcast)
#pragma unroll
            for (int j = 0; j < 8; j++) v[j] = hr[j] + hc[j] + radial * wr[j];
#pragma unroll
            for (int m = 0; m < 8; m++) {
                float we[8];
                load8(sW + (1 + m) * 128 + q * 64 + u * 8, we);  // ea rows (broadcast)
#pragma unroll
                for (int j = 0; j < 8; j++) v[j] = fmaf(eav[m], we[j], v[j]);
            }
#pragma unroll
            for (int j = 0; j < 8; j++) v[j] = fmaxf(v[j], 0.f);
            store8(dst + u * 8, v);
        }
    }
    __syncthreads();

    // ---- MLP2: 8x8 register tile ----
    const int tr8 = tid & 7, jb = (tid >> 3) * 8;
    float acc[8][8];
    zero88(acc);
    gemm_tile8<128>(sH, 132, w2, HID, tr8, jb, acc);
    float bb[8]; load8(b2 + jb, bb);
    __syncthreads();               // all gemm reads of sH complete before overwrite

    // ---- write relu(feat) tile back to LDS ----
#pragma unroll
    for (int i = 0; i < 8; i++) {
        float v[8];
#pragma unroll
        for (int j = 0; j < 8; j++) v[j] = fmaxf(acc[i][j] + bb[j], 0.f);
        store8(sH + (tr8 + 8 * i) * 132 + jb, v);
    }
    __syncthreads();

    // ---- segmented reduction: 2 passes of 32 slots, 4 threads (32ch) per slot ----
#pragma unroll
    for (int base = 0; base < 64; base += 32) {
        const int s = base + (tid >> 2), q4 = tid & 3;
        const int r = sRow[s];
        const bool head = (s == 0) || (sRow[s - 1] != r);
        if (head) {
            float sum[32];
            const float* src = sH + s * 132 + q4 * 32;
#pragma unroll
            for (int j = 0; j < 32; j += 4) {
                float4 t = *(const float4*)(src + j);
                sum[j] = t.x; sum[j+1] = t.y; sum[j+2] = t.z; sum[j+3] = t.w;
            }
            int L = 1;
            while (s + L < 64 && sRow[s + L] == r) {
                const float* p = sH + (s + L) * 132 + q4 * 32;
#pragma unroll
                for (int j = 0; j < 32; j += 4) {
                    float4 t = *(const float4*)(p + j);
                    sum[j] += t.x; sum[j+1] += t.y; sum[j+2] += t.z; sum[j+3] += t.w;
                }
                L++;
            }
            float* dst = agg + (size_t)r * HID + q4 * 32;
            const bool interior = (row_ptr[r] >= e0) && (row_ptr[r + 1] <= e0 + 64);
            if (interior) {     // this tile holds ALL edges of row r -> plain store
#pragma unroll
                for (int j = 0; j < 32; j += 4)
                    *(float4*)(dst + j) = make_float4(sum[j], sum[j+1], sum[j+2], sum[j+3]);
            } else {            // row spans tiles -> atomic (rare: ~2 rows/tile)
#pragma unroll
                for (int j = 0; j < 32; j++) atomicAdd(dst + j, sum[j]);
            }
        }
    }
}

// ---------------- kernel 3: node model ----------------
// out = relu(concat(x, agg) @ w_n1 + b_n1) @ w_n2 + b_n2
// 128 threads, 8x8 register tile (proven structure from edge r7).
// agg aliases out: each block stages its rows into LDS before overwriting them.
__global__ __launch_bounds__(128, 2)
void node_kernel(const float* __restrict__ x, const float* agg,
                 const float* __restrict__ w1, const float* __restrict__ b1,
                 const float* __restrict__ w2, const float* __restrict__ b2,
                 float* out, int N) {
    __shared__ float sA[64 * 260];
    const int tid = threadIdx.x;
    const int n0  = blockIdx.x * 64;
    {
        const int n = tid >> 1, q = tid & 1;
        int gn = n0 + n; if (gn >= N) gn = N - 1;
        const float4* src = q ? (const float4*)(agg + (size_t)gn * HID)
                              : (const float4*)(x   + (size_t)gn * CH);
        float4* dst = (float4*)(sA + n * 260 + q * CH);
#pragma unroll
        for (int u = 0; u < 32; u++) dst[u] = src[u];
    }
    __syncthreads();
    const int tr8 = tid & 7, jb = (tid >> 3) * 8;
    float acc[8][8];
    zero88(acc);
    gemm_tile8<256>(sA, 260, w1, HID, tr8, jb, acc);
    float bb[8]; load8(b1 + jb, bb);
    float h[8][8];
#pragma unroll
    for (int i = 0; i < 8; i++)
#pragma unroll
        for (int j = 0; j < 8; j++) h[i][j] = fmaxf(acc[i][j] + bb[j], 0.f);
    __syncthreads();   // all MLP1 reads of sA complete
#pragma unroll
    for (int i = 0; i < 8; i++) store8(sA + (tr8 + 8 * i) * 260 + jb, h[i]);
    __syncthreads();
    zero88(acc);
    gemm_tile8<128>(sA, 260, w2, CH, tr8, jb, acc);
    float b2v[8]; load8(b2 + jb, b2v);
#pragma unroll
    for (int i = 0; i < 8; i++) {
        const int gn = n0 + tr8 + 8 * i;
        if (gn < N) {
            float v[8];
#pragma unroll
            for (int j = 0; j < 8; j++) v[j] = acc[i][j] + b2v[j];
            store8(out + (size_t)gn * CH + jb, v);
        }
    }
}

// ---------------- launch ----------------
extern "C" void kernel_launch(void* const* d_in, const int* in_sizes, int n_in,
                              void* d_out, int out_size, void* d_ws, size_t ws_size,
                              hipStream_t stream) {
    const float* x     = (const float*)d_in[0];
    const float* coord = (const float*)d_in[1];
    const int*   ei    = (const int*)d_in[2];   // [2,E]: row = ei[0:E], col = ei[E:2E]
    const float* ea    = (const float*)d_in[3];
    const float* w_e1  = (const float*)d_in[4];
    const float* b_e1  = (const float*)d_in[5];
    const float* w_e2  = (const float*)d_in[6];
    const float* b_e2  = (const float*)d_in[7];
    const float* w_n1  = (const float*)d_in[8];
    const float* b_n1  = (const float*)d_in[9];
    const float* w_n2  = (const float*)d_in[10];
    const float* b_n2  = (const float*)d_in[11];

    const int N = in_sizes[0] / CH;
    const int E = in_sizes[2] / 2;

    float* out = (float*)d_out;
    float* agg = out;                 // agg lives in d_out, aliased

    // workspace carve (all 16B-aligned): tbl | perm | deg | row_ptr | cursor
    char* w = (char*)d_ws;
    float* tbl   = (float*)w;  w += (size_t)N * 256 * sizeof(float);   // 51.2 MB
    int* perm    = (int*)w;    w += (size_t)E * sizeof(int);           // 2.4 MB
    int* deg     = (int*)w;    w += (size_t)N * sizeof(int);
    int* row_ptr = (int*)w;    w += (size_t)(N + 1) * sizeof(int);
    int* cursor  = (int*)w;

    hipMemsetAsync(agg, 0, (size_t)N * HID * sizeof(float), stream);
    hipMemsetAsync(deg, 0, (size_t)N * sizeof(int), stream);

    precompute_kernel<<<dim3((N + 63) / 64), dim3(128), 0, stream>>>(x, w_e1, b_e1, tbl, N);
    hist_kernel<<<dim3((E + 255) / 256), dim3(256), 0, stream>>>(ei, deg, E);
    scan_kernel<<<dim3(1), dim3(1024), 0, stream>>>(deg, row_ptr, cursor, N);
    scatter_kernel<<<dim3((E + 255) / 256), dim3(256), 0, stream>>>(ei, cursor, perm, E);
    edge_kernel_sorted<<<dim3(E / 64), dim3(128), 0, stream>>>(tbl, coord, ei, ea,
                                                               w_e1, w_e2, b_e2,
                                                               perm, row_ptr, agg, E);
    node_kernel<<<dim3((N + 63) / 64), dim3(128), 0, stream>>>(x, agg, w_n1, b_n1,
                                                               w_n2, b_n2, out, N);
}

// Round 11
// 666.171 us; speedup vs baseline: 3.6336x; 1.1253x over previous
//
#include <hip/hip_runtime.h>

#define CH  128   // C: node feature channels
#define HID 128   // H: hidden channels
#define EAD 8     // edge_attr dim

typedef __attribute__((ext_vector_type(8))) short short8v;   // 8 bf16 (4 VGPRs)
typedef __attribute__((ext_vector_type(4))) float floatx4;   // MFMA acc

// ---------------- helpers ----------------
__device__ __forceinline__ void load8(const float* __restrict__ p, float* r) {
    float4 v0 = *(const float4*)p;
    float4 v1 = *(const float4*)(p + 4);
    r[0]=v0.x; r[1]=v0.y; r[2]=v0.z; r[3]=v0.w;
    r[4]=v1.x; r[5]=v1.y; r[6]=v1.z; r[7]=v1.w;
}
__device__ __forceinline__ void store8(float* p, const float* v) {
    *(float4*)p       = make_float4(v[0], v[1], v[2], v[3]);
    *(float4*)(p + 4) = make_float4(v[4], v[5], v[6], v[7]);
}
__device__ __forceinline__ void zero88(float a[8][8]) {
#pragma unroll
    for (int i = 0; i < 8; i++)
#pragma unroll
        for (int j = 0; j < 8; j++) a[i][j] = 0.f;
}
__device__ __forceinline__ unsigned short f2bf(float f) {   // RNE float->bf16 bits
    union { float f; unsigned u; } v; v.f = f;
    return (unsigned short)((v.u + 0x7FFFu + ((v.u >> 16) & 1u)) >> 16);
}
__device__ __forceinline__ float bf2f(unsigned short h) {
    union { unsigned u; float f; } v; v.u = ((unsigned)h) << 16;
    return v.f;
}

// 64-row x 128-col GEMM accumulate, 8x8 register tile, 128 threads (fp32 FMA).
template <int K>
__device__ __forceinline__ void gemm_tile8(const float* sA, int strideA,
                                           const float* __restrict__ B, int ldb,
                                           int tr8, int jb, float acc[8][8]) {
#pragma unroll 2
    for (int k = 0; k < K; k += 4) {
        float av[8][4];
#pragma unroll
        for (int i = 0; i < 8; i++) {
            float4 t = *(const float4*)(sA + (tr8 + 8 * i) * strideA + k);
            av[i][0] = t.x; av[i][1] = t.y; av[i][2] = t.z; av[i][3] = t.w;
        }
#pragma unroll
        for (int kk = 0; kk < 4; kk++) {
            float b8[8];
            load8(B + (size_t)(k + kk) * ldb + jb, b8);
#pragma unroll
            for (int i = 0; i < 8; i++)
#pragma unroll
                for (int j = 0; j < 8; j++)
                    acc[i][j] = fmaf(av[i][kk], b8[j], acc[i][j]);
        }
    }
}

// ---------------- kernel 1: per-node factored edge-MLP1 partials ----------------
__global__ __launch_bounds__(128, 2)
void precompute_kernel(const float* __restrict__ x, const float* __restrict__ w1,
                       const float* __restrict__ b1, float* __restrict__ tbl, int N) {
    __shared__ float sX[64 * 132];
    const int tid = threadIdx.x;
    const int n0  = blockIdx.x * 64;
    {
        const int n = tid >> 1, q = tid & 1;
        int gn = n0 + n; if (gn >= N) gn = N - 1;
        const float4* src = (const float4*)(x + (size_t)gn * CH + q * 64);
        float4* dst = (float4*)(sX + n * 132 + q * 64);
#pragma unroll
        for (int u = 0; u < 16; u++) dst[u] = src[u];
    }
    __syncthreads();
    const int tr8 = tid & 7, jb = (tid >> 3) * 8;
    float acc[8][8];

    zero88(acc);
    gemm_tile8<128>(sX, 132, w1, HID, tr8, jb, acc);          // rows 0..127 of w_e1
    float bb[8]; load8(b1 + jb, bb);
#pragma unroll
    for (int i = 0; i < 8; i++) {
        const int gn = n0 + tr8 + 8 * i;
        if (gn < N) {
            float v[8];
#pragma unroll
            for (int j = 0; j < 8; j++) v[j] = acc[i][j] + bb[j];
            store8(tbl + (size_t)gn * 256 + jb, v);
        }
    }

    zero88(acc);
    gemm_tile8<128>(sX, 132, w1 + CH * HID, HID, tr8, jb, acc); // rows 128..255
#pragma unroll
    for (int i = 0; i < 8; i++) {
        const int gn = n0 + tr8 + 8 * i;
        if (gn < N) store8(tbl + (size_t)gn * 256 + 128 + jb, acc[i]);
    }
}

// ---------------- CSR build: histogram -> scan -> scatter ----------------
__global__ void hist_kernel(const int* __restrict__ ei, int* __restrict__ deg, int E) {
    const int e = blockIdx.x * blockDim.x + threadIdx.x;
    if (e < E) atomicAdd(&deg[ei[e]], 1);
}

__global__ void scan_kernel(const int* __restrict__ deg, int* __restrict__ row_ptr,
                            int* __restrict__ cursor, int N) {
    __shared__ int part[1024];
    const int tid = threadIdx.x;
    const int chunk = (N + 1023) / 1024;
    const int lo = tid * chunk;
    const int hi = (lo + chunk < N) ? lo + chunk : N;
    int s = 0;
    for (int i = lo; i < hi; i++) s += deg[i];
    part[tid] = s;
    __syncthreads();
    for (int off = 1; off < 1024; off <<= 1) {   // Hillis-Steele inclusive scan
        int v = (tid >= off) ? part[tid - off] : 0;
        __syncthreads();
        part[tid] += v;
        __syncthreads();
    }
    int run = (tid == 0) ? 0 : part[tid - 1];    // exclusive base
    for (int i = lo; i < hi; i++) {
        row_ptr[i] = run; cursor[i] = run;
        run += deg[i];
    }
    if (tid == 1023) row_ptr[N] = run;           // total = E
}

__global__ void scatter_kernel(const int* __restrict__ ei, int* cursor,
                               int* __restrict__ perm, int E) {
    const int e = blockIdx.x * blockDim.x + threadIdx.x;
    if (e < E) {
        const int p = atomicAdd(&cursor[ei[e]], 1);
        perm[p] = e;
    }
}

// ---------------- prep: w2 (f32, [k][n]) -> w2t (bf16, [n][k] transposed) --------
__global__ void prep_w2t(const float* __restrict__ w2, unsigned short* __restrict__ w2t) {
    const int idx = blockIdx.x * 256 + threadIdx.x;   // 16384 total
    const int n = idx >> 7, k = idx & 127;
    w2t[idx] = f2bf(w2[k * HID + n]);
}

// ---------------- kernel 2: edge model, MFMA MLP2 + segmented reduce ----------
// h1 staged as bf16 in LDS (stride 136 -> 16B rows, bank-balanced frag reads).
// MLP2: D = H[64x128] x W2[128x128] via mfma_f32_16x16x32_bf16; 2 waves split
// the 128 output cols; each wave: 4x4 16x16 C-tiles x K-loop(4) = 64 MFMAs.
// C/D layout (m89/m91): col=lane&15, row=(lane>>4)*4+reg.
__global__ __launch_bounds__(128, 2)
void edge_kernel_sorted(const float* __restrict__ tbl, const float* __restrict__ coord,
                        const int* __restrict__ ei, const float* __restrict__ ea,
                        const float* __restrict__ w1,
                        const unsigned short* __restrict__ w2t,
                        const float* __restrict__ b2, const int* __restrict__ perm,
                        const int* __restrict__ row_ptr, float* agg, int E) {
    __shared__ __align__(16) unsigned short sHu[64 * 136];  // h1/feat tile, bf16
    __shared__ float sW[9 * 128];   // w_e1 rows 256..264 (radial + edge_attr), f32
    __shared__ int   sRow[64];      // sorted row id per tile slot
    const int tid = threadIdx.x;

    // bijective XCD swizzle (m204)
    const int nwg = gridDim.x;
    const int qq = nwg >> 3, rr = nwg & 7;
    const int xcd = blockIdx.x & 7, idx = blockIdx.x >> 3;
    const int wg  = (xcd < rr) ? (xcd * (qq + 1) + idx)
                               : (rr * (qq + 1) + (xcd - rr) * qq + idx);
    const int e0  = wg * 64;           // E % 64 == 0: no tail

    for (int i = tid; i < 9 * 128; i += 128) sW[i] = w1[256 * HID + i];
    __syncthreads();

    // ---- stage h1 tile (bf16): 2 threads per edge slot, 64 channels each ----
    {
        const int s = tid >> 1, q = tid & 1;
        const int pe = perm[e0 + s];           // original edge id
        const int r = ei[pe];
        const int c = ei[E + pe];
        if (q == 0) sRow[s] = r;
        const float dx = coord[3 * r + 0] - coord[3 * c + 0];
        const float dy = coord[3 * r + 1] - coord[3 * c + 1];
        const float dz = coord[3 * r + 2] - coord[3 * c + 2];
        const float radial = fmaf(dx, dx, fmaf(dy, dy, dz * dz));
        float eav[8];
        load8(ea + (size_t)pe * EAD, eav);
        const float* tr = tbl + (size_t)r * 256 + q * 64;        // row partial (+b_e1)
        const float* tc = tbl + (size_t)c * 256 + 128 + q * 64;  // col partial
        unsigned short* dst = sHu + s * 136 + q * 64;
#pragma unroll
        for (int u = 0; u < 8; u++) {
            float hr[8], hc[8], wr[8], v[8];
            load8(tr + u * 8, hr);
            load8(tc + u * 8, hc);
            load8(sW + q * 64 + u * 8, wr);                      // radial row (broadcast)
#pragma unroll
            for (int j = 0; j < 8; j++) v[j] = hr[j] + hc[j] + radial * wr[j];
#pragma unroll
            for (int m = 0; m < 8; m++) {
                float we[8];
                load8(sW + (1 + m) * 128 + q * 64 + u * 8, we);  // ea rows (broadcast)
#pragma unroll
                for (int j = 0; j < 8; j++) v[j] = fmaf(eav[m], we[j], v[j]);
            }
            short8v t;
#pragma unroll
            for (int j = 0; j < 8; j++) t[j] = (short)f2bf(fmaxf(v[j], 0.f));
            *(short8v*)(dst + u * 8) = t;
        }
    }
    __syncthreads();

    // ---- MLP2 via MFMA ----
    const int lane = tid & 63;
    const int wcol = (tid >> 6) * 64;      // wave 0: cols 0..63, wave 1: 64..127
    const int lr = lane & 15;              // A-row / B-col / C-col within tile
    const int lg = lane >> 4;              // k-group / C-row-group
    floatx4 acc[4][4];                     // [mt][ct]
#pragma unroll
    for (int mt = 0; mt < 4; mt++)
#pragma unroll
        for (int ct = 0; ct < 4; ct++)
#pragma unroll
            for (int j = 0; j < 4; j++) acc[mt][ct][j] = 0.f;

#pragma unroll
    for (int kc = 0; kc < 4; kc++) {
        short8v afr[4];                    // A[mt*16+lr][kc*32+lg*8 .. +8]
#pragma unroll
        for (int mt = 0; mt < 4; mt++)
            afr[mt] = *(const short8v*)(sHu + (mt * 16 + lr) * 136 + kc * 32 + lg * 8);
        short8v bfr[4];                    // B[kc*32+lg*8..][wcol+ct*16+lr] from w2t[n][k]
#pragma unroll
        for (int ct = 0; ct < 4; ct++)
            bfr[ct] = *(const short8v*)(w2t + (size_t)(wcol + ct * 16 + lr) * HID
                                            + kc * 32 + lg * 8);
#pragma unroll
        for (int mt = 0; mt < 4; mt++)
#pragma unroll
            for (int ct = 0; ct < 4; ct++)
                acc[mt][ct] = __builtin_amdgcn_mfma_f32_16x16x32_bf16(
                                  afr[mt], bfr[ct], acc[mt][ct], 0, 0, 0);
    }

    float b2v[4];
#pragma unroll
    for (int ct = 0; ct < 4; ct++) b2v[ct] = b2[wcol + ct * 16 + lr];
    __syncthreads();               // all A-fragment reads done before overwrite

    // ---- write relu(feat) back to LDS (bf16) ----
#pragma unroll
    for (int mt = 0; mt < 4; mt++)
#pragma unroll
        for (int ct = 0; ct < 4; ct++)
#pragma unroll
            for (int r_ = 0; r_ < 4; r_++) {
                const int row = mt * 16 + lg * 4 + r_;
                const int col = wcol + ct * 16 + lr;
                sHu[row * 136 + col] = f2bf(fmaxf(acc[mt][ct][r_] + b2v[ct], 0.f));
            }
    __syncthreads();

    // ---- segmented reduction: 2 passes of 32 slots, 4 threads (32ch) per slot ----
#pragma unroll
    for (int base = 0; base < 64; base += 32) {
        const int s = base + (tid >> 2), q4 = tid & 3;
        const int r = sRow[s];
        const bool head = (s == 0) || (sRow[s - 1] != r);
        if (head) {
            float sum[32];
            {
                const short8v* sp = (const short8v*)(sHu + s * 136 + q4 * 32);
#pragma unroll
                for (int v8 = 0; v8 < 4; v8++) {
                    short8v t = sp[v8];
#pragma unroll
                    for (int j = 0; j < 8; j++)
                        sum[v8 * 8 + j] = bf2f((unsigned short)t[j]);
                }
            }
            int L = 1;
            while (s + L < 64 && sRow[s + L] == r) {
                const short8v* sp = (const short8v*)(sHu + (s + L) * 136 + q4 * 32);
#pragma unroll
                for (int v8 = 0; v8 < 4; v8++) {
                    short8v t = sp[v8];
#pragma unroll
                    for (int j = 0; j < 8; j++)
                        sum[v8 * 8 + j] += bf2f((unsigned short)t[j]);
                }
                L++;
            }
            float* dst = agg + (size_t)r * HID + q4 * 32;
            const bool interior = (row_ptr[r] >= e0) && (row_ptr[r + 1] <= e0 + 64);
            if (interior) {     // this tile holds ALL edges of row r -> plain store
#pragma unroll
                for (int j = 0; j < 32; j += 4)
                    *(float4*)(dst + j) = make_float4(sum[j], sum[j+1], sum[j+2], sum[j+3]);
            } else {            // row spans tiles -> atomic (rare: ~2 rows/tile)
#pragma unroll
                for (int j = 0; j < 32; j++) atomicAdd(dst + j, sum[j]);
            }
        }
    }
}

// ---------------- kernel 3: node model ----------------
__global__ __launch_bounds__(128, 2)
void node_kernel(const float* __restrict__ x, const float* agg,
                 const float* __restrict__ w1, const float* __restrict__ b1,
                 const float* __restrict__ w2, const float* __restrict__ b2,
                 float* out, int N) {
    __shared__ float sA[64 * 260];
    const int tid = threadIdx.x;
    const int n0  = blockIdx.x * 64;
    {
        const int n = tid >> 1, q = tid & 1;
        int gn = n0 + n; if (gn >= N) gn = N - 1;
        const float4* src = q ? (const float4*)(agg + (size_t)gn * HID)
                              : (const float4*)(x   + (size_t)gn * CH);
        float4* dst = (float4*)(sA + n * 260 + q * CH);
#pragma unroll
        for (int u = 0; u < 32; u++) dst[u] = src[u];
    }
    __syncthreads();
    const int tr8 = tid & 7, jb = (tid >> 3) * 8;
    float acc[8][8];
    zero88(acc);
    gemm_tile8<256>(sA, 260, w1, HID, tr8, jb, acc);
    float bb[8]; load8(b1 + jb, bb);
    float h[8][8];
#pragma unroll
    for (int i = 0; i < 8; i++)
#pragma unroll
        for (int j = 0; j < 8; j++) h[i][j] = fmaxf(acc[i][j] + bb[j], 0.f);
    __syncthreads();   // all MLP1 reads of sA complete
#pragma unroll
    for (int i = 0; i < 8; i++) store8(sA + (tr8 + 8 * i) * 260 + jb, h[i]);
    __syncthreads();
    zero88(acc);
    gemm_tile8<128>(sA, 260, w2, CH, tr8, jb, acc);
    float b2v[8]; load8(b2 + jb, b2v);
#pragma unroll
    for (int i = 0; i < 8; i++) {
        const int gn = n0 + tr8 + 8 * i;
        if (gn < N) {
            float v[8];
#pragma unroll
            for (int j = 0; j < 8; j++) v[j] = acc[i][j] + b2v[j];
            store8(out + (size_t)gn * CH + jb, v);
        }
    }
}

// ---------------- launch ----------------
extern "C" void kernel_launch(void* const* d_in, const int* in_sizes, int n_in,
                              void* d_out, int out_size, void* d_ws, size_t ws_size,
                              hipStream_t stream) {
    const float* x     = (const float*)d_in[0];
    const float* coord = (const float*)d_in[1];
    const int*   ei    = (const int*)d_in[2];   // [2,E]: row = ei[0:E], col = ei[E:2E]
    const float* ea    = (const float*)d_in[3];
    const float* w_e1  = (const float*)d_in[4];
    const float* b_e1  = (const float*)d_in[5];
    const float* w_e2  = (const float*)d_in[6];
    const float* b_e2  = (const float*)d_in[7];
    const float* w_n1  = (const float*)d_in[8];
    const float* b_n1  = (const float*)d_in[9];
    const float* w_n2  = (const float*)d_in[10];
    const float* b_n2  = (const float*)d_in[11];

    const int N = in_sizes[0] / CH;
    const int E = in_sizes[2] / 2;

    float* out = (float*)d_out;
    float* agg = out;                 // agg lives in d_out, aliased

    // workspace carve (all 16B-aligned): tbl | perm | w2t | deg | row_ptr | cursor
    char* w = (char*)d_ws;
    float* tbl   = (float*)w;          w += (size_t)N * 256 * sizeof(float);  // 51.2 MB
    int* perm    = (int*)w;            w += (size_t)E * sizeof(int);          // 2.4 MB
    unsigned short* w2t = (unsigned short*)w;  w += (size_t)HID * HID * 2;    // 32 KB
    int* deg     = (int*)w;            w += (size_t)N * sizeof(int);
    int* row_ptr = (int*)w;            w += (size_t)(N + 1) * sizeof(int);
    int* cursor  = (int*)w;

    hipMemsetAsync(agg, 0, (size_t)N * HID * sizeof(float), stream);
    hipMemsetAsync(deg, 0, (size_t)N * sizeof(int), stream);

    precompute_kernel<<<dim3((N + 63) / 64), dim3(128), 0, stream>>>(x, w_e1, b_e1, tbl, N);
    prep_w2t<<<dim3(HID * HID / 256), dim3(256), 0, stream>>>(w_e2, w2t);
    hist_kernel<<<dim3((E + 255) / 256), dim3(256), 0, stream>>>(ei, deg, E);
    scan_kernel<<<dim3(1), dim3(1024), 0, stream>>>(deg, row_ptr, cursor, N);
    scatter_kernel<<<dim3((E + 255) / 256), dim3(256), 0, stream>>>(ei, cursor, perm, E);
    edge_kernel_sorted<<<dim3(E / 64), dim3(128), 0, stream>>>(tbl, coord, ei, ea,
                                                               w_e1, w2t, b_e2,
                                                               perm, row_ptr, agg, E);
    node_kernel<<<dim3((N + 63) / 64), dim3(128), 0, stream>>>(x, agg, w_n1, b_n1,
                                                               w_n2, b_n2, out, N);
}